// Round 1
// baseline (700.088 us; speedup 1.0000x reference)
//
#include <hip/hip_runtime.h>
#include <hip/hip_bf16.h>

#define TD_B 512
#define TD_N 32
#define TD_T 20
#define TD_E 16
#define TD_H 32
#define TD_A 32
#define TD_MLP 128

__device__ __forceinline__ float sigf(float x) { return 1.0f / (1.0f + __expf(-x)); }
__device__ __forceinline__ float tanhfast(float x) { return 2.0f / (1.0f + __expf(-2.0f * x)) - 1.0f; }

extern "C" __global__ void __launch_bounds__(512, 2)
traj_disc_kernel(const float* __restrict__ x, const float* __restrict__ dmat,
                 const float* __restrict__ bmat, const float* __restrict__ hmat,
                 const float* __restrict__ mask,
                 const float* __restrict__ emb_w, const float* __restrict__ emb_b,
                 const float* __restrict__ w_ih, const float* __restrict__ w_hh,
                 const float* __restrict__ b_ih, const float* __restrict__ b_hh,
                 const float* __restrict__ e2a_w, const float* __restrict__ e2a_b,
                 const float* __restrict__ dom,
                 const float* __restrict__ sp_w, const float* __restrict__ sp_b,
                 const float* __restrict__ a2e_w, const float* __restrict__ a2e_b,
                 const float* __restrict__ w1, const float* __restrict__ b1,
                 const float* __restrict__ w2, const float* __restrict__ b2,
                 const float* __restrict__ w3, const float* __restrict__ b3,
                 float* __restrict__ out)
{
    const int b = blockIdx.x;
    const int tid = threadIdx.x;

    __shared__ float sWih[TD_E][TD_H * 4];        // [e][h*4+g] = w_ih[e][g*32+h]
    __shared__ float sWhh[TD_H][TD_H * 4];        // [k][h*4+g] = w_hh[k][g*32+h]
    __shared__ float sB4[TD_H * 4];               // combined bias, gate-interleaved
    __shared__ float sE2A[TD_H][TD_A];
    __shared__ float sE2Ab[TD_A];
    __shared__ float sSp[2 * TD_A][TD_A];
    __shared__ float sSpb[TD_A];
    __shared__ float sA2E[TD_A][TD_H];
    __shared__ float sA2Eb[TD_H];
    __shared__ float sDom[144];
    __shared__ float sEmbW[2][TD_E];
    __shared__ float sEmbB[TD_E];
    __shared__ float sXe[TD_N][TD_E];
    __shared__ float sMask[TD_N];
    __shared__ float sWmat[TD_N][TD_N + 1];       // padded for row-sum bank spread
    __shared__ float sWinv[TD_N];
    __shared__ float sH[TD_N][TD_H];
    __shared__ float sC[TD_N][TD_H];
    __shared__ float sHl[TD_N][TD_H];
    __shared__ float sHa[TD_N][TD_A];
    __shared__ float sAtt[TD_N][TD_A];
    __shared__ float sEmb[TD_N][TD_A];
    __shared__ __hip_bfloat16 sHs[TD_T][TD_N][TD_H];  // 40 KB history (bf16)
    __shared__ float sZ1[TD_N][TD_MLP];
    __shared__ float sZ2[TD_N][TD_MLP + 1];       // padded for row reads in final dot

    // ---- load weights into LDS (one-time) ----
    for (int idx = tid; idx < TD_E * TD_H * 4; idx += 512) {
        int e = idx >> 7, r = idx & 127, hh = r >> 2, g = r & 3;
        (&sWih[0][0])[idx] = w_ih[e * 128 + g * 32 + hh];
    }
    for (int idx = tid; idx < TD_H * TD_H * 4; idx += 512) {
        int k = idx >> 7, r = idx & 127, hh = r >> 2, g = r & 3;
        (&sWhh[0][0])[idx] = w_hh[k * 128 + g * 32 + hh];
    }
    if (tid < 128) { int hh = tid >> 2, g = tid & 3; sB4[tid] = b_ih[g * 32 + hh] + b_hh[g * 32 + hh]; }
    for (int idx = tid; idx < TD_H * TD_A; idx += 512) (&sE2A[0][0])[idx] = e2a_w[idx];
    for (int idx = tid; idx < 2 * TD_A * TD_A; idx += 512) (&sSp[0][0])[idx] = sp_w[idx];
    for (int idx = tid; idx < TD_A * TD_H; idx += 512) (&sA2E[0][0])[idx] = a2e_w[idx];
    if (tid < 32) { sE2Ab[tid] = e2a_b[tid]; sSpb[tid] = sp_b[tid]; sA2Eb[tid] = a2e_b[tid]; }
    if (tid < 144) sDom[tid] = dom[tid];
    if (tid < 32) sEmbW[tid >> 4][tid & 15] = emb_w[tid];
    if (tid >= 32 && tid < 48) sEmbB[tid - 32] = emb_b[tid - 32];
    for (int idx = tid; idx < TD_N * TD_H; idx += 512) { (&sH[0][0])[idx] = 0.f; (&sC[0][0])[idx] = 0.f; }
    __syncthreads();

    const int h  = tid & 31;   // column within H/A
    const int n0 = tid >> 5;   // 0..15 (each thread covers rows n0 and n0+16)

    for (int t = 0; t < TD_T; ++t) {
        // phase 1: xe = x @ emb_w + emb_b ; load mask
        {
            int n = tid >> 4, e = tid & 15;
            float x0 = x[((b * TD_N + n) * TD_T + t) * 2 + 0];
            float x1 = x[((b * TD_N + n) * TD_T + t) * 2 + 1];
            sXe[n][e] = x0 * sEmbW[0][e] + x1 * sEmbW[1][e] + sEmbB[e];
        }
        if (tid < 32) sMask[tid] = mask[(b * TD_N + tid) * TD_T + t];
        __syncthreads();

        // phase 2: attention weight matrix
        for (int eidx = tid; eidx < TD_N * TD_N; eidx += 512) {
            int i = eidx >> 5, j = eidx & 31;
            long base = ((long)(b * TD_N + i) * TD_T + t) * TD_N + j;
            float d  = dmat[base];
            float bb = bmat[base];
            float hd = hmat[base];
            int ib = (int)floorf(bb / 30.0f);  ib = ib < 0 ? 0 : (ib > 11 ? 11 : ib);
            int ii = (int)floorf(hd / 30.0f);  ii = ii < 0 ? 0 : (ii > 11 ? 11 : ii);
            float wv = sDom[ib * 12 + ii] - d;
            wv = wv > 0.f ? wv : 0.f;
            wv *= sMask[i] * sMask[j];
            sWmat[i][j] = wv;
        }
        __syncthreads();

        // phase 3: row-sum inverses (first 32 threads) + LSTM gates/cell (all threads)
        if (tid < 32) {
            float s = 0.f;
            #pragma unroll
            for (int j = 0; j < TD_N; ++j) s += sWmat[tid][j];
            sWinv[tid] = 1.0f / (s + 1e-8f);
        }
        #pragma unroll
        for (int cc = 0; cc < 2; ++cc) {
            int n = n0 + 16 * cc;
            float gi = sB4[h * 4 + 0], gf = sB4[h * 4 + 1];
            float gg = sB4[h * 4 + 2], go = sB4[h * 4 + 3];
            #pragma unroll
            for (int e = 0; e < TD_E; ++e) {
                float xv = sXe[n][e];
                float4 w = *(const float4*)&sWih[e][h * 4];
                gi += xv * w.x; gf += xv * w.y; gg += xv * w.z; go += xv * w.w;
            }
            #pragma unroll
            for (int k = 0; k < TD_H; ++k) {
                float hv = sH[n][k];
                float4 w = *(const float4*)&sWhh[k][h * 4];
                gi += hv * w.x; gf += hv * w.y; gg += hv * w.z; go += hv * w.w;
            }
            float cn = sigf(gf) * sC[n][h] + sigf(gi) * tanhfast(gg);
            sC[n][h] = cn;
            sHl[n][h] = sigf(go) * tanhfast(cn);
        }
        __syncthreads();

        // phase 4: ha = h_lstm @ enc2att + b
        #pragma unroll
        for (int cc = 0; cc < 2; ++cc) {
            int n = n0 + 16 * cc;
            float acc = sE2Ab[h];
            #pragma unroll
            for (int k = 0; k < TD_H; ++k) acc += sHl[n][k] * sE2A[k][h];
            sHa[n][h] = acc;
        }
        __syncthreads();

        // phase 5: att = norm(w) @ ha
        #pragma unroll
        for (int cc = 0; cc < 2; ++cc) {
            int i = n0 + 16 * cc;
            float acc = 0.f;
            #pragma unroll
            for (int j = 0; j < TD_N; ++j) acc += sWmat[i][j] * sHa[j][h];
            sAtt[i][h] = acc * sWinv[i];
        }
        __syncthreads();

        // phase 6: emb = tanh([ha, att] @ spemb + b)
        #pragma unroll
        for (int cc = 0; cc < 2; ++cc) {
            int n = n0 + 16 * cc;
            float acc = sSpb[h];
            #pragma unroll
            for (int a = 0; a < TD_A; ++a) acc += sHa[n][a] * sSp[a][h];
            #pragma unroll
            for (int a = 0; a < TD_A; ++a) acc += sAtt[n][a] * sSp[TD_A + a][h];
            sEmb[n][h] = tanhfast(acc);
        }
        __syncthreads();

        // phase 7: h_new = emb @ att2enc + b ; record history
        #pragma unroll
        for (int cc = 0; cc < 2; ++cc) {
            int n = n0 + 16 * cc;
            float acc = sA2Eb[h];
            #pragma unroll
            for (int a = 0; a < TD_A; ++a) acc += sEmb[n][a] * sA2E[a][h];
            sH[n][h] = acc;
            sHs[t][n][h] = __float2bfloat16(acc);
        }
        __syncthreads();
    }

    // ---- MLP head ----
    {
        int m = tid & 127;
        int nb = tid >> 7;  // 0..3
        float acc[8];
        #pragma unroll
        for (int q = 0; q < 8; ++q) acc[q] = b1[m];
        for (int idx = 0; idx < TD_T * TD_H; ++idx) {
            float wv = w1[idx * TD_MLP + m];
            int tt = idx >> 5, k = idx & 31;
            #pragma unroll
            for (int q = 0; q < 8; ++q)
                acc[q] += wv * __bfloat162float(sHs[tt][nb * 8 + q][k]);
        }
        #pragma unroll
        for (int q = 0; q < 8; ++q) {
            float v = acc[q];
            sZ1[nb * 8 + q][m] = v > 0.f ? v : 0.2f * v;
        }
    }
    __syncthreads();
    {
        int m = tid & 127;
        int nb = tid >> 7;
        float acc[8];
        #pragma unroll
        for (int q = 0; q < 8; ++q) acc[q] = b2[m];
        for (int idx = 0; idx < TD_MLP; ++idx) {
            float wv = w2[idx * TD_MLP + m];
            #pragma unroll
            for (int q = 0; q < 8; ++q)
                acc[q] += wv * sZ1[nb * 8 + q][idx];
        }
        #pragma unroll
        for (int q = 0; q < 8; ++q) {
            float v = acc[q];
            sZ2[nb * 8 + q][m] = v > 0.f ? v : 0.2f * v;
        }
    }
    __syncthreads();
    if (tid < 32) {
        float acc = b3[0];
        for (int mm = 0; mm < TD_MLP; ++mm) acc += sZ2[tid][mm] * w3[mm];
        out[b * TD_N + tid] = sigf(acc);
    }
}

extern "C" void kernel_launch(void* const* d_in, const int* in_sizes, int n_in,
                              void* d_out, int out_size, void* d_ws, size_t ws_size,
                              hipStream_t stream) {
    (void)in_sizes; (void)n_in; (void)d_ws; (void)ws_size; (void)out_size;
    const float* x     = (const float*)d_in[0];
    const float* dmat  = (const float*)d_in[1];
    const float* bmat  = (const float*)d_in[2];
    const float* hmat  = (const float*)d_in[3];
    const float* mask  = (const float*)d_in[4];
    const float* emb_w = (const float*)d_in[5];
    const float* emb_b = (const float*)d_in[6];
    const float* w_ih  = (const float*)d_in[7];
    const float* w_hh  = (const float*)d_in[8];
    const float* b_ih  = (const float*)d_in[9];
    const float* b_hh  = (const float*)d_in[10];
    const float* e2a_w = (const float*)d_in[11];
    const float* e2a_b = (const float*)d_in[12];
    const float* dom   = (const float*)d_in[13];
    const float* sp_w  = (const float*)d_in[14];
    const float* sp_b  = (const float*)d_in[15];
    const float* a2e_w = (const float*)d_in[16];
    const float* a2e_b = (const float*)d_in[17];
    const float* w1    = (const float*)d_in[18];
    const float* b1    = (const float*)d_in[19];
    const float* w2    = (const float*)d_in[20];
    const float* b2    = (const float*)d_in[21];
    const float* w3    = (const float*)d_in[22];
    const float* b3    = (const float*)d_in[23];
    float* out = (float*)d_out;

    traj_disc_kernel<<<dim3(TD_B), dim3(512), 0, stream>>>(
        x, dmat, bmat, hmat, mask, emb_w, emb_b, w_ih, w_hh, b_ih, b_hh,
        e2a_w, e2a_b, dom, sp_w, sp_b, a2e_w, a2e_b,
        w1, b1, w2, b2, w3, b3, out);
}

// Round 2
// 80.125 us; speedup vs baseline: 8.7374x; 8.7374x over previous
//
#include <hip/hip_runtime.h>
#include <hip/hip_bf16.h>

#define TD_B 512
#define TD_N 32
#define TD_T 20

typedef __bf16 bf16x8 __attribute__((ext_vector_type(8)));
typedef __bf16 bf16x4 __attribute__((ext_vector_type(4)));
typedef float  f32x4  __attribute__((ext_vector_type(4)));

#define MFMA(a, b, c) __builtin_amdgcn_mfma_f32_16x16x32_bf16((a), (b), (c), 0, 0, 0)

__device__ __forceinline__ float sigf(float x)  { return 1.0f / (1.0f + __expf(-x)); }
__device__ __forceinline__ float tanhf_(float x){ return 2.0f / (1.0f + __expf(-2.0f * x)) - 1.0f; }

extern "C" __global__ void __launch_bounds__(256, 2)
traj_disc_kernel(const float* __restrict__ x, const float* __restrict__ dmat,
                 const float* __restrict__ bmat, const float* __restrict__ hmat,
                 const float* __restrict__ mask,
                 const float* __restrict__ emb_w, const float* __restrict__ emb_b,
                 const float* __restrict__ w_ih, const float* __restrict__ w_hh,
                 const float* __restrict__ b_ih, const float* __restrict__ b_hh,
                 const float* __restrict__ e2a_w, const float* __restrict__ e2a_b,
                 const float* __restrict__ dom,
                 const float* __restrict__ sp_w, const float* __restrict__ sp_b,
                 const float* __restrict__ a2e_w, const float* __restrict__ a2e_b,
                 const float* __restrict__ w1, const float* __restrict__ b1,
                 const float* __restrict__ w2, const float* __restrict__ b2,
                 const float* __restrict__ w3, const float* __restrict__ b3,
                 float* __restrict__ out)
{
    const int b   = blockIdx.x;
    const int tid = threadIdx.x;
    const int lane = tid & 63;
    const int w    = tid >> 6;     // wave 0..3
    const int l15  = lane & 15;
    const int lg   = lane >> 4;    // 0..3

    // ---- LDS tiles (bf16 rows padded to 16B multiples; f32 padded) ----
    __shared__ __bf16 sAin[32][80];    // cols 0-15 xe | 16-47 h | 48-63 zero | pad
    __shared__ float  sGate[32][136];  // gates f32, col = 4h+g; aliased by z-tiles at tail
    __shared__ __bf16 sHl[32][40];     // h_lstm
    __shared__ __bf16 sPA[32][80];     // cols 0-31 ha | 32-63 att
    __shared__ __bf16 sHaT[32][40];    // ha transposed (for B-frag reads)
    __shared__ __bf16 sEmb[32][40];
    __shared__ float  sWmat[32][36];   // raw relu(dom-d)
    __shared__ __bf16 sWN[32][40];     // normalized, masked, bf16
    __shared__ float  sMask[32][21];
    __shared__ float  sMcur[32];
    __shared__ float  sDom[144];
    __shared__ float  sEmbW[3][16];    // rows 0,1: emb_w; row 2: emb_b
    __shared__ float  sBias4[128];     // gate-interleaved combined LSTM bias
    __shared__ float  sBiasE[32], sBiasS[32], sBiasA[32];

    // ================= P0: one-time staging =================
    for (int idx = tid; idx < 32 * 80; idx += 256) (&sAin[0][0])[idx] = (__bf16)0.0f;
    for (int idx = tid; idx < 640; idx += 256) {
        int n = idx / 20, tt = idx % 20;
        sMask[n][tt] = mask[(b * TD_N + n) * TD_T + tt];
    }
    if (tid < 144) sDom[tid] = dom[tid];
    if (tid < 32)  sEmbW[tid >> 4][tid & 15] = emb_w[tid];
    if (tid >= 32 && tid < 48) sEmbW[2][tid - 32] = emb_b[tid - 32];
    if (tid < 128) { int hh = tid >> 2, g = tid & 3; sBias4[tid] = b_ih[g * 32 + hh] + b_hh[g * 32 + hh]; }
    if (tid < 32) { sBiasE[tid] = e2a_b[tid]; sBiasS[tid] = sp_b[tid]; sBiasA[tid] = a2e_b[tid]; }

    // ---- persistent weight B-fragments (bf16, in registers for all steps) ----
    // gates B [64][128], gate-interleaved cols c=4h+g -> src col (c&3)*32+(c>>2)
    bf16x8 Bg[2][2];
    #pragma unroll
    for (int kt = 0; kt < 2; ++kt)
        #pragma unroll
        for (int ntp = 0; ntp < 2; ++ntp) {
            int c = (2 * w + ntp) * 16 + l15;
            int cg = (c & 3) * 32 + (c >> 2);
            #pragma unroll
            for (int j = 0; j < 8; ++j) {
                int row = kt * 32 + lg * 8 + j;
                float v = (row < 16) ? w_ih[row * 128 + cg]
                         : (row < 48) ? w_hh[(row - 16) * 128 + cg] : 0.0f;
                Bg[kt][ntp][j] = (__bf16)v;
            }
        }
    const int mtw = w >> 1, ntw = w & 1;      // tile owned by this wave in 4-tile phases
    const int cw  = ntw * 16 + l15;           // output column in those phases
    bf16x8 Be2a, Ba2e, Bsp[2];
    #pragma unroll
    for (int j = 0; j < 8; ++j) {
        int row = lg * 8 + j;
        Be2a[j] = (__bf16)e2a_w[row * 32 + cw];
        Ba2e[j] = (__bf16)a2e_w[row * 32 + cw];
    }
    #pragma unroll
    for (int kt = 0; kt < 2; ++kt)
        #pragma unroll
        for (int j = 0; j < 8; ++j)
            Bsp[kt][j] = (__bf16)sp_w[(kt * 32 + lg * 8 + j) * 32 + cw];

    // per-thread LSTM cell state: thread (h=tid&31, nb=tid>>5) owns rows nb+8r
    const int hI = tid & 31, nb = tid >> 5;
    float cst[4] = {0.f, 0.f, 0.f, 0.f};
    f32x4 accZ[2][2] = {};   // online z1 accumulators [mt][ntp]

    __syncthreads();

    for (int t = 0; t < TD_T; ++t) {
        // ================= P1 =================
        bf16x8 Bw1[2];
        if (t >= 1) {  // w1 slice for z1 of h_{t-1}; issued early, used after barrier
            #pragma unroll
            for (int ntp = 0; ntp < 2; ++ntp) {
                int c = (2 * w + ntp) * 16 + l15;
                #pragma unroll
                for (int j = 0; j < 8; ++j)
                    Bw1[ntp][j] = (__bf16)w1[((t - 1) * 32 + lg * 8 + j) * 128 + c];
            }
        }
        {   // raw spatial weights
            int i = tid >> 3, p = tid & 7;
            int base = ((b * TD_N + i) * TD_T + t) * TD_N + 4 * p;
            float4 dv = *(const float4*)(dmat + base);
            float4 bv = *(const float4*)(bmat + base);
            float4 hv = *(const float4*)(hmat + base);
            float4 wv;
            #pragma unroll
            for (int q = 0; q < 4; ++q) {
                float bq = (&bv.x)[q], hq = (&hv.x)[q];
                int ib = (int)floorf(bq * (1.0f / 30.0f)); ib = ib < 0 ? 0 : (ib > 11 ? 11 : ib);
                int ih = (int)floorf(hq * (1.0f / 30.0f)); ih = ih < 0 ? 0 : (ih > 11 ? 11 : ih);
                float v = sDom[ib * 12 + ih] - (&dv.x)[q];
                (&wv.x)[q] = v > 0.f ? v : 0.f;
            }
            *(float4*)&sWmat[i][4 * p] = wv;
        }
        {   // xe = x @ emb_w + emb_b  -> sAin cols 0-15
            int n = tid >> 3, e2 = tid & 7;
            float x0 = x[((b * TD_N + n) * TD_T + t) * 2 + 0];
            float x1 = x[((b * TD_N + n) * TD_T + t) * 2 + 1];
            #pragma unroll
            for (int q = 0; q < 2; ++q) {
                int e = 2 * e2 + q;
                sAin[n][e] = (__bf16)(x0 * sEmbW[0][e] + x1 * sEmbW[1][e] + sEmbW[2][e]);
            }
        }
        if (tid < 32) sMcur[tid] = sMask[tid][t];
        __syncthreads();

        // ================= P2: gates MFMA + z1 MFMA + normalize =================
        #pragma unroll
        for (int mt = 0; mt < 2; ++mt) {
            bf16x8 a0 = *(const bf16x8*)&sAin[mt * 16 + l15][lg * 8];
            bf16x8 a1 = *(const bf16x8*)&sAin[mt * 16 + l15][32 + lg * 8];
            #pragma unroll
            for (int ntp = 0; ntp < 2; ++ntp) {
                f32x4 cc = {0.f, 0.f, 0.f, 0.f};
                cc = MFMA(a0, Bg[0][ntp], cc);
                cc = MFMA(a1, Bg[1][ntp], cc);
                int c = (2 * w + ntp) * 16 + l15;
                #pragma unroll
                for (int q = 0; q < 4; ++q)
                    sGate[mt * 16 + lg * 4 + q][c] = cc[q];
            }
        }
        if (t >= 1) {
            #pragma unroll
            for (int mt = 0; mt < 2; ++mt) {
                bf16x8 ah = *(const bf16x8*)&sAin[mt * 16 + l15][16 + lg * 8];
                #pragma unroll
                for (int ntp = 0; ntp < 2; ++ntp)
                    accZ[mt][ntp] = MFMA(ah, Bw1[ntp], accZ[mt][ntp]);
            }
        }
        {   // normalize + mask -> bf16 wN
            int i = tid >> 3, p = tid & 7;
            float4 wv = *(const float4*)&sWmat[i][4 * p];
            float4 mj = *(const float4*)&sMcur[4 * p];
            float  mi = sMcur[i];
            float s = wv.x * mj.x + wv.y * mj.y + wv.z * mj.z + wv.w * mj.w;
            s += __shfl_xor(s, 1); s += __shfl_xor(s, 2); s += __shfl_xor(s, 4);
            float inv = mi / (mi * s + 1e-8f);
            #pragma unroll
            for (int q = 0; q < 4; ++q)
                sWN[i][4 * p + q] = (__bf16)((&wv.x)[q] * (&mj.x)[q] * inv);
        }
        __syncthreads();

        // ================= P3: LSTM cell (c in registers) =================
        {
            float4 bb = *(const float4*)&sBias4[4 * hI];
            #pragma unroll
            for (int r = 0; r < 4; ++r) {
                int n = nb + 8 * r;
                float4 gv = *(const float4*)&sGate[n][4 * hI];
                float gi = gv.x + bb.x, gf = gv.y + bb.y, gg = gv.z + bb.z, go = gv.w + bb.w;
                float cn = sigf(gf) * cst[r] + sigf(gi) * tanhf_(gg);
                cst[r] = cn;
                sHl[n][hI] = (__bf16)(sigf(go) * tanhf_(cn));
            }
        }
        __syncthreads();

        // ================= P4: ha = hl @ e2a (+b) -> sPA[:,0:32] and sHaT =================
        {
            bf16x8 a = *(const bf16x8*)&sHl[mtw * 16 + l15][lg * 8];
            f32x4 cc = {0.f, 0.f, 0.f, 0.f};
            cc = MFMA(a, Be2a, cc);
            float bias = sBiasE[cw];
            bf16x4 tv;
            #pragma unroll
            for (int q = 0; q < 4; ++q) {
                float v = cc[q] + bias;
                sPA[mtw * 16 + lg * 4 + q][cw] = (__bf16)v;
                tv[q] = (__bf16)v;
            }
            *(bf16x4*)&sHaT[cw][mtw * 16 + lg * 4] = tv;
        }
        __syncthreads();

        // ================= P5: att = wN @ ha -> sPA[:,32:64] =================
        {
            bf16x8 a  = *(const bf16x8*)&sWN[mtw * 16 + l15][lg * 8];
            bf16x8 bb = *(const bf16x8*)&sHaT[cw][lg * 8];   // B-frag via transpose
            f32x4 cc = {0.f, 0.f, 0.f, 0.f};
            cc = MFMA(a, bb, cc);
            #pragma unroll
            for (int q = 0; q < 4; ++q)
                sPA[mtw * 16 + lg * 4 + q][32 + cw] = (__bf16)cc[q];
        }
        __syncthreads();

        // ================= P6: emb = tanh([ha|att] @ sp + b) =================
        {
            bf16x8 a0 = *(const bf16x8*)&sPA[mtw * 16 + l15][lg * 8];
            bf16x8 a1 = *(const bf16x8*)&sPA[mtw * 16 + l15][32 + lg * 8];
            f32x4 cc = {0.f, 0.f, 0.f, 0.f};
            cc = MFMA(a0, Bsp[0], cc);
            cc = MFMA(a1, Bsp[1], cc);
            float bias = sBiasS[cw];
            #pragma unroll
            for (int q = 0; q < 4; ++q)
                sEmb[mtw * 16 + lg * 4 + q][cw] = (__bf16)tanhf_(cc[q] + bias);
        }
        __syncthreads();

        // ================= P7: h_new = emb @ a2e + b -> sAin cols 16-47 =================
        {
            bf16x8 a = *(const bf16x8*)&sEmb[mtw * 16 + l15][lg * 8];
            f32x4 cc = {0.f, 0.f, 0.f, 0.f};
            cc = MFMA(a, Ba2e, cc);
            float bias = sBiasA[cw];
            #pragma unroll
            for (int q = 0; q < 4; ++q)
                sAin[mtw * 16 + lg * 4 + q][16 + cw] = (__bf16)(cc[q] + bias);
        }
        __syncthreads();
    }

    // ================= tail: z1 for t=19 =================
    {
        bf16x8 Bw1[2];
        #pragma unroll
        for (int ntp = 0; ntp < 2; ++ntp) {
            int c = (2 * w + ntp) * 16 + l15;
            #pragma unroll
            for (int j = 0; j < 8; ++j)
                Bw1[ntp][j] = (__bf16)w1[(19 * 32 + lg * 8 + j) * 128 + c];
        }
        #pragma unroll
        for (int mt = 0; mt < 2; ++mt) {
            bf16x8 ah = *(const bf16x8*)&sAin[mt * 16 + l15][16 + lg * 8];
            #pragma unroll
            for (int ntp = 0; ntp < 2; ++ntp)
                accZ[mt][ntp] = MFMA(ah, Bw1[ntp], accZ[mt][ntp]);
        }
    }
    // z1 + b1, leaky -> z1bf (aliases sGate)
    __bf16* z1bf = (__bf16*)&sGate[0][0];       // [32][136]
    __bf16* z2bf = z1bf + 32 * 136;             // [32][136]
    #pragma unroll
    for (int mt = 0; mt < 2; ++mt)
        #pragma unroll
        for (int ntp = 0; ntp < 2; ++ntp) {
            int c = (2 * w + ntp) * 16 + l15;
            float bias = b1[c];
            #pragma unroll
            for (int q = 0; q < 4; ++q) {
                float v = accZ[mt][ntp][q] + bias;
                v = v > 0.f ? v : 0.2f * v;
                z1bf[(mt * 16 + lg * 4 + q) * 136 + c] = (__bf16)v;
            }
        }
    __syncthreads();

    // z2 = leaky(z1 @ w2 + b2), K=128
    {
        f32x4 c2[2][2] = {};
        #pragma unroll
        for (int kt = 0; kt < 4; ++kt) {
            bf16x8 a[2];
            #pragma unroll
            for (int mt = 0; mt < 2; ++mt)
                a[mt] = *(const bf16x8*)&z1bf[(mt * 16 + l15) * 136 + kt * 32 + lg * 8];
            bf16x8 bb[2];
            #pragma unroll
            for (int ntp = 0; ntp < 2; ++ntp) {
                int c = (2 * w + ntp) * 16 + l15;
                #pragma unroll
                for (int j = 0; j < 8; ++j)
                    bb[ntp][j] = (__bf16)w2[(kt * 32 + lg * 8 + j) * 128 + c];
            }
            #pragma unroll
            for (int mt = 0; mt < 2; ++mt)
                #pragma unroll
                for (int ntp = 0; ntp < 2; ++ntp)
                    c2[mt][ntp] = MFMA(a[mt], bb[ntp], c2[mt][ntp]);
        }
        #pragma unroll
        for (int mt = 0; mt < 2; ++mt)
            #pragma unroll
            for (int ntp = 0; ntp < 2; ++ntp) {
                int c = (2 * w + ntp) * 16 + l15;
                float bias = b2[c];
                #pragma unroll
                for (int q = 0; q < 4; ++q) {
                    float v = c2[mt][ntp][q] + bias;
                    v = v > 0.f ? v : 0.2f * v;
                    z2bf[(mt * 16 + lg * 4 + q) * 136 + c] = (__bf16)v;
                }
            }
    }
    __syncthreads();

    // z3 = sigmoid(z2 @ w3 + b3)
    {
        int n = tid >> 3, kg = tid & 7;
        bf16x8 v0 = *(const bf16x8*)&z2bf[n * 136 + kg * 16];
        bf16x8 v1 = *(const bf16x8*)&z2bf[n * 136 + kg * 16 + 8];
        float s = 0.f;
        #pragma unroll
        for (int j = 0; j < 8; ++j)
            s += (float)v0[j] * w3[kg * 16 + j] + (float)v1[j] * w3[kg * 16 + 8 + j];
        s += __shfl_xor(s, 1); s += __shfl_xor(s, 2); s += __shfl_xor(s, 4);
        if (kg == 0) out[b * TD_N + n] = 1.0f / (1.0f + __expf(-(s + b3[0])));
    }
}

extern "C" void kernel_launch(void* const* d_in, const int* in_sizes, int n_in,
                              void* d_out, int out_size, void* d_ws, size_t ws_size,
                              hipStream_t stream) {
    (void)in_sizes; (void)n_in; (void)d_ws; (void)ws_size; (void)out_size;
    const float* x     = (const float*)d_in[0];
    const float* dmat  = (const float*)d_in[1];
    const float* bmat  = (const float*)d_in[2];
    const float* hmat  = (const float*)d_in[3];
    const float* mask  = (const float*)d_in[4];
    const float* emb_w = (const float*)d_in[5];
    const float* emb_b = (const float*)d_in[6];
    const float* w_ih  = (const float*)d_in[7];
    const float* w_hh  = (const float*)d_in[8];
    const float* b_ih  = (const float*)d_in[9];
    const float* b_hh  = (const float*)d_in[10];
    const float* e2a_w = (const float*)d_in[11];
    const float* e2a_b = (const float*)d_in[12];
    const float* dom   = (const float*)d_in[13];
    const float* sp_w  = (const float*)d_in[14];
    const float* sp_b  = (const float*)d_in[15];
    const float* a2e_w = (const float*)d_in[16];
    const float* a2e_b = (const float*)d_in[17];
    const float* w1    = (const float*)d_in[18];
    const float* b1    = (const float*)d_in[19];
    const float* w2    = (const float*)d_in[20];
    const float* b2    = (const float*)d_in[21];
    const float* w3    = (const float*)d_in[22];
    const float* b3    = (const float*)d_in[23];
    float* out = (float*)d_out;

    traj_disc_kernel<<<dim3(TD_B), dim3(256), 0, stream>>>(
        x, dmat, bmat, hmat, mask, emb_w, emb_b, w_ih, w_hh, b_ih, b_hh,
        e2a_w, e2a_b, dom, sp_w, sp_b, a2e_w, a2e_b,
        w1, b1, w2, b2, w3, b3, out);
}